// Round 2
// baseline (1274.834 us; speedup 1.0000x reference)
//
#include <hip/hip_runtime.h>
#include <math.h>

#define EMB 2048
#define HD 128
#define SEQ 2048
#define MTOT 8192   // B*S

typedef __bf16 bf16x8 __attribute__((ext_vector_type(8)));
typedef float floatx4 __attribute__((ext_vector_type(4)));

__device__ __forceinline__ unsigned short f2bf(float f) {
    unsigned u = __float_as_uint(f);
    return (unsigned short)((u + 0x7FFFu + ((u >> 16) & 1u)) >> 16);  // RNE
}

// async global->LDS, 16B per lane. LDS dest must be wave-uniform base + lane*16.
__device__ __forceinline__ void gl_lds16(const void* g, void* lds) {
    __builtin_amdgcn_global_load_lds(
        (const __attribute__((address_space(1))) unsigned int*)g,
        (__attribute__((address_space(3))) unsigned int*)lds,
        16, 0, 0);
}

// ---------------- fused fp32 -> bf16 cast: x + 4 weights, one dispatch ------
__global__ void cast_all_kernel(const float* __restrict__ x,
                                const float* __restrict__ w0,
                                const float* __restrict__ w1,
                                const float* __restrict__ w2,
                                const float* __restrict__ w3,
                                unsigned short* __restrict__ xb,
                                unsigned short* __restrict__ wb0,
                                unsigned short* __restrict__ wb1,
                                unsigned short* __restrict__ wb2,
                                unsigned short* __restrict__ wb3)
{
    const int XN4 = MTOT * EMB / 4;       // 4,194,304
    const int WN4 = EMB * EMB / 4;        // 1,048,576
    int i = blockIdx.x * blockDim.x + threadIdx.x;
    const float* src; unsigned short* dst; int off;
    if (i < XN4) { src = x; dst = xb; off = i; }
    else {
        int j = i - XN4;
        int wsel = j >> 20;               // / WN4
        off = j & (WN4 - 1);
        switch (wsel) {
            case 0: src = w0; dst = wb0; break;
            case 1: src = w1; dst = wb1; break;
            case 2: src = w2; dst = wb2; break;
            default: src = w3; dst = wb3; break;
        }
    }
    float4 v = reinterpret_cast<const float4*>(src)[off];
    ushort4 o;
    o.x = f2bf(v.x); o.y = f2bf(v.y); o.z = f2bf(v.z); o.w = f2bf(v.w);
    reinterpret_cast<ushort4*>(dst)[off] = o;
}

// ---------------- C[M,N] = A[M,K] * Bw[N,K]^T  (bf16 MFMA) ------------------
// 256x256 tile, BK=64, 512 threads = 8 waves (2M x 4N), each wave 128x64.
// 8-phase schedule (T3+T4): one half-tile (16KB) staged per phase via
// global_load_lds w=16; counted vmcnt(4) at phases 4/8 only (never 0 in the
// main loop); raw s_barrier + lgkmcnt(0) per phase; setprio(1) around the
// 16-MFMA cluster (T5). LDS XOR swizzle (T2): byte ^= ((row&7)<<4), applied
// BOTH on the pre-swizzled global source of gl_lds16 and on ds_read addrs
// (rule 21: both-sides-or-neither) -> 2 lanes/bank on the stride-128B
// fragment reads (free per m136).
//
// Staging sequence: half-tile #s, ht(t,j): t=K-tile (64 wide, buffer t&1),
// j: 0=A rows 0-127, 1=A rows 128-255, 2=B rows 0-127, 3=B rows 128-255.
// Prologue stages #0..5; iteration i phase p stages #(5+8i+p).
// WAR: every half's restage slot is >=1 barrier after its last drained read
// (A halves read ph1/ph2, restaged ph3/ph4; B halves read ph1/ph3, restaged
// ph5/ph6; buf1 mirrored). RAW: vmcnt(4) leaves only the 2 newest half-tile
// stages (= next K-tile's A halves) in flight; barrier after vmcnt gives
// cross-wave visibility. Tail iteration: ph3/ph4 stages guard off -> its ph4
// uses vmcnt(0). Accumulation order identical to 32-step baseline.

#define PH_PRE()  do { asm volatile("s_barrier" ::: "memory");               \
                       asm volatile("s_waitcnt lgkmcnt(0)" ::: "memory");    \
                       __builtin_amdgcn_sched_barrier(0);                    \
                       __builtin_amdgcn_s_setprio(1); } while (0)
#define PH_POST() do { __builtin_amdgcn_s_setprio(0);                        \
                       asm volatile("s_barrier" ::: "memory"); } while (0)

#define MFMA16(AF, BF, MI0)                                                  \
    _Pragma("unroll")                                                        \
    for (int mi = 0; mi < 4; mi++)                                           \
        _Pragma("unroll")                                                    \
        for (int ni = 0; ni < 4; ni++)                                       \
            acc[(MI0) + mi][ni] = __builtin_amdgcn_mfma_f32_16x16x32_bf16(   \
                AF[(MI0) + mi], BF[ni], acc[(MI0) + mi][ni], 0, 0, 0);

template<bool OUT_F32>
__global__ __launch_bounds__(512, 2)
void gemm256_bt(const unsigned short* __restrict__ A,
                const unsigned short* __restrict__ Bw0,
                const unsigned short* __restrict__ Bw1,
                const unsigned short* __restrict__ Bw2,
                void* __restrict__ Cout0,
                void* __restrict__ Cout1,
                void* __restrict__ Cout2,
                const float* __restrict__ bias,
                int M, int N, int K, float scale0)
{
    __shared__ __align__(16) unsigned short sA[2][256][64];   // 64 KB
    __shared__ __align__(16) unsigned short sB[2][256][64];   // 64 KB

    const unsigned short* Bw = (blockIdx.z == 0) ? Bw0 : (blockIdx.z == 1) ? Bw1 : Bw2;
    void* Cout = (blockIdx.z == 0) ? Cout0 : (blockIdx.z == 1) ? Cout1 : Cout2;
    const float osc = (blockIdx.z == 0) ? scale0 : 1.0f;

    const int tid  = threadIdx.x;
    const int lane = tid & 63;
    const int wave = tid >> 6;      // 0..7
    const int wm   = wave >> 2;     // 0..1  (M half)
    const int wn   = wave & 3;      // 0..3  (N quarter)
    const int col  = lane & 15;
    const int quad = lane >> 4;

    const int m0 = blockIdx.y * 256;
    const int n0 = blockIdx.x * 256;

    const int NT     = K >> 6;      // K-tiles of 64
    const int NITER  = NT >> 1;     // 2 K-tiles per iteration
    const int fourNT = NT << 2;

    // per-thread staging coords: thread covers 16B chunks (tid) and (tid+512)
    // of each 16KB half-tile. P = linear byte in half; source col pre-swizzled.
    int sr[2], sc[2];
    #pragma unroll
    for (int q = 0; q < 2; q++) {
        int P = (tid + (q << 9)) << 4;
        int r = P >> 7;                                // row 0..127
        sr[q] = r;
        sc[q] = ((P & 127) ^ ((r & 7) << 4)) >> 1;     // element col
    }

    floatx4 acc[8][4];
    #pragma unroll
    for (int i = 0; i < 8; i++)
        #pragma unroll
        for (int j = 0; j < 4; j++)
            #pragma unroll
            for (int r = 0; r < 4; r++) acc[i][j][r] = 0.0f;

    auto STAGE = [&](int s) {
        if (s >= fourNT) return;                       // tail guard (uniform)
        int t = s >> 2, j = s & 3;
        int buf = t & 1;
        int k0 = t << 6;
        const unsigned short* src;
        unsigned short* region;
        int row0;
        if (j < 2) { src = A;  region = &sA[buf][j << 7][0];       row0 = m0 + (j << 7); }
        else       { src = Bw; region = &sB[buf][(j - 2) << 7][0]; row0 = n0 + ((j - 2) << 7); }
        #pragma unroll
        for (int q = 0; q < 2; q++) {
            // LDS dest: wave-uniform base + lane*16 (HW adds lane offset)
            char* ldsb = (char*)region + (((wave << 6) + (q << 9)) << 4);
            gl_lds16(src + (size_t)(row0 + sr[q]) * K + (k0 + sc[q]), ldsb);
        }
    };

    const char* sAc = (const char*)&sA[0][0][0];
    const char* sBc = (const char*)&sB[0][0][0];
    auto LDA = [&](int buf, int mi, int kk) -> bf16x8 {
        int R  = (wm << 7) + (mi << 4) + col;
        int lo = (R << 7) + (kk << 6) + (quad << 4);
        int po = lo ^ ((R & 7) << 4);
        return *reinterpret_cast<const bf16x8*>(sAc + (buf << 15) + po);
    };
    auto LDB = [&](int buf, int ni, int kk) -> bf16x8 {
        int R  = (wn << 6) + (ni << 4) + col;
        int lo = (R << 7) + (kk << 6) + (quad << 4);
        int po = lo ^ ((R & 7) << 4);
        return *reinterpret_cast<const bf16x8*>(sBc + (buf << 15) + po);
    };

    // ---- prologue: stage #0..5 = buf0 all 4 halves + buf1 A-h0, A-h1
    #pragma unroll
    for (int s = 0; s < 6; s++) STAGE(s);
    asm volatile("s_waitcnt vmcnt(4)" ::: "memory");   // K-tile 0 complete
    asm volatile("s_barrier" ::: "memory");

    #pragma unroll 1
    for (int it = 0; it < NITER; ++it) {
        const int sbase = 5 + (it << 3);
        bf16x8 af0[8], af1[8], bf0[4], bf1[4];

        // ============ buf0 : K-tile 2*it ============
        // phase 1: 12 reads, MFMA mi0-3 kk0
        #pragma unroll
        for (int mi = 0; mi < 8; mi++) af0[mi] = LDA(0, mi, 0);
        #pragma unroll
        for (int ni = 0; ni < 4; ni++) bf0[ni] = LDB(0, ni, 0);
        STAGE(sbase + 1);
        PH_PRE();
        MFMA16(af0, bf0, 0);
        PH_POST();

        // phase 2: 8 reads, MFMA mi4-7 kk0
        #pragma unroll
        for (int mi = 0; mi < 8; mi++) af1[mi] = LDA(0, mi, 1);
        STAGE(sbase + 2);
        PH_PRE();
        MFMA16(af0, bf0, 4);
        PH_POST();

        // phase 3: 4 reads, MFMA mi0-3 kk1
        #pragma unroll
        for (int ni = 0; ni < 4; ni++) bf1[ni] = LDB(0, ni, 1);
        STAGE(sbase + 3);
        PH_PRE();
        MFMA16(af1, bf1, 0);
        PH_POST();

        // phase 4: 0 reads, MFMA mi4-7 kk1; vmcnt covers buf1 for ph5
        STAGE(sbase + 4);
        if (it < NITER - 1) { asm volatile("s_waitcnt vmcnt(4)" ::: "memory"); }
        else                { asm volatile("s_waitcnt vmcnt(0)" ::: "memory"); }
        PH_PRE();
        MFMA16(af1, bf1, 4);
        PH_POST();

        // ============ buf1 : K-tile 2*it+1 ============
        // phase 5
        #pragma unroll
        for (int mi = 0; mi < 8; mi++) af0[mi] = LDA(1, mi, 0);
        #pragma unroll
        for (int ni = 0; ni < 4; ni++) bf0[ni] = LDB(1, ni, 0);
        STAGE(sbase + 5);
        PH_PRE();
        MFMA16(af0, bf0, 0);
        PH_POST();

        // phase 6
        #pragma unroll
        for (int mi = 0; mi < 8; mi++) af1[mi] = LDA(1, mi, 1);
        STAGE(sbase + 6);
        PH_PRE();
        MFMA16(af0, bf0, 4);
        PH_POST();

        // phase 7
        #pragma unroll
        for (int ni = 0; ni < 4; ni++) bf1[ni] = LDB(1, ni, 1);
        STAGE(sbase + 7);
        PH_PRE();
        MFMA16(af1, bf1, 0);
        PH_POST();

        // phase 8: vmcnt covers next iteration's buf0
        STAGE(sbase + 8);
        asm volatile("s_waitcnt vmcnt(4)" ::: "memory");
        PH_PRE();
        MFMA16(af1, bf1, 4);
        PH_POST();
    }

    // ---- epilogue: same C/D mapping as the verified baseline
    #pragma unroll
    for (int mi = 0; mi < 8; mi++) {
        #pragma unroll
        for (int ni = 0; ni < 4; ni++) {
            #pragma unroll
            for (int r = 0; r < 4; r++) {
                int row = m0 + (wm << 7) + (mi << 4) + (quad << 2) + r;
                int cg  = n0 + (wn << 6) + (ni << 4) + col;
                float v = acc[mi][ni][r];
                if (OUT_F32) {
                    float bb = bias ? bias[cg] : 0.0f;
                    reinterpret_cast<float*>(Cout)[(size_t)row * N + cg] = v + bb;
                } else {
                    reinterpret_cast<unsigned short*>(Cout)[(size_t)row * N + cg] = f2bf(v * osc);
                }
            }
        }
    }
}

// ---------------- causal flash attention, S^T formulation ----------------
// (unchanged, verified)
__global__ __launch_bounds__(256, 2)
void flash_attn(const unsigned short* __restrict__ Q,
                const unsigned short* __restrict__ Kg,
                const unsigned short* __restrict__ Vg,
                unsigned short* __restrict__ O)
{
    __shared__ __align__(16) unsigned short sK[64 * 128];
    __shared__ __align__(16) unsigned short sVt[128][72];   // [d][key], padded
    __shared__ __align__(16) unsigned short sP[4][16 * 72]; // [q][key], per-wave

    const int tid  = threadIdx.x;
    const int lane = tid & 63;
    const int w    = tid >> 6;
    const int col  = lane & 15;
    const int quad = lane >> 4;

    const int h = blockIdx.y;
    const int b = blockIdx.z;
    const size_t rowbase = (size_t)b * SEQ;
    const int hoff = h * HD;

    unsigned short* sPw = sP[w];

    const int vk4 = (tid & 15) * 4;
    const int vd0 = (tid >> 4) * 8;

    #pragma unroll
    for (int phase = 0; phase < 2; phase++) {
        const int qsb = phase ? (int)blockIdx.x : (SEQ/128 - 1) - (int)blockIdx.x;
        const int qbase = qsb * 128;
        const int qg0 = qbase + w*32 + col;
        const int qg1 = qg0 + 16;

        bf16x8 qf[2][4];
        {
            const unsigned short* qr0 = Q + (rowbase + qg0) * EMB + hoff;
            const unsigned short* qr1 = Q + (rowbase + qg1) * EMB + hoff;
            #pragma unroll
            for (int ks = 0; ks < 4; ks++) {
                qf[0][ks] = *reinterpret_cast<const bf16x8*>(qr0 + ks*32 + quad*8);
                qf[1][ks] = *reinterpret_cast<const bf16x8*>(qr1 + ks*32 + quad*8);
            }
        }

        floatx4 oacc[2][8];
        #pragma unroll
        for (int g = 0; g < 2; g++)
            #pragma unroll
            for (int ni = 0; ni < 8; ni++)
                #pragma unroll
                for (int r = 0; r < 4; r++) oacc[g][ni][r] = 0.0f;
        float l_i[2] = {0.0f, 0.0f};

        const int ktmax = qbase / 64 + 1;
        for (int kt = 0; kt <= ktmax; kt++) {
            const int k0 = kt * 64;
            #pragma unroll
            for (int i = 0; i < 4; i++) {
                int c = tid + i * 256;
                int key = c >> 4;
                int dblk = (c & 15) ^ (key & 7);
                char* ldsK = (char*)sK + (size_t)(i * 256 + w * 64) * 16;
                gl_lds16(Kg + (rowbase + k0 + key) * EMB + hoff + dblk * 8, ldsK);
            }
            {
                unsigned short va[4][8];
                #pragma unroll
                for (int kk = 0; kk < 4; kk++)
                    *reinterpret_cast<int4*>(va[kk]) =
                        *reinterpret_cast<const int4*>(Vg + (rowbase + k0 + vk4 + kk) * EMB + hoff + vd0);
                #pragma unroll
                for (int j = 0; j < 8; j++) {
                    ushort4 o;
                    o.x = va[0][j]; o.y = va[1][j]; o.z = va[2][j]; o.w = va[3][j];
                    *reinterpret_cast<ushort4*>(&sVt[vd0 + j][vk4]) = o;
                }
            }
            __syncthreads();

            if (k0 <= qbase + w*32 + 31) {
                floatx4 sc[2][4];
                #pragma unroll
                for (int g = 0; g < 2; g++)
                    #pragma unroll
                    for (int ni = 0; ni < 4; ni++)
                        #pragma unroll
                        for (int r = 0; r < 4; r++) sc[g][ni][r] = 0.0f;
                #pragma unroll
                for (int ni = 0; ni < 4; ni++) {
                    #pragma unroll
                    for (int ks = 0; ks < 4; ks++) {
                        int u = (ni*16 + col) * 16 + ((ks*4 + quad) ^ (col & 7));
                        bf16x8 kf = *reinterpret_cast<const bf16x8*>(&sK[u * 8]);
                        sc[0][ni] = __builtin_amdgcn_mfma_f32_16x16x32_bf16(kf, qf[0][ks], sc[0][ni], 0, 0, 0);
                        sc[1][ni] = __builtin_amdgcn_mfma_f32_16x16x32_bf16(kf, qf[1][ks], sc[1][ni], 0, 0, 0);
                    }
                }

                const bool need_mask = (k0 + 63 > qbase + w*32);
                bf16x8 pf[2][2];

                #pragma unroll
                for (int g = 0; g < 2; g++) {
                    const int qg = (g == 0) ? qg0 : qg1;
                    if (need_mask) {
                        #pragma unroll
                        for (int ni = 0; ni < 4; ni++)
                            #pragma unroll
                            for (int r = 0; r < 4; r++) {
                                int key = k0 + ni*16 + quad*4 + r;
                                if (key > qg) sc[g][ni][r] = -1e30f;
                            }
                    }
                    float rsum = 0.0f;
                    #pragma unroll
                    for (int ni = 0; ni < 4; ni++) {
                        float p0 = __expf(sc[g][ni][0]);
                        float p1 = __expf(sc[g][ni][1]);
                        float p2 = __expf(sc[g][ni][2]);
                        float p3 = __expf(sc[g][ni][3]);
                        rsum += (p0 + p1) + (p2 + p3);
                        ushort4 pk;
                        pk.x = f2bf(p0); pk.y = f2bf(p1); pk.z = f2bf(p2); pk.w = f2bf(p3);
                        *reinterpret_cast<ushort4*>(&sPw[col*72 + ni*16 + quad*4]) = pk;
                    }
                    l_i[g] += rsum;
                    #pragma unroll
                    for (int ks = 0; ks < 2; ks++)
                        pf[g][ks] = *reinterpret_cast<const bf16x8*>(&sPw[col*72 + ks*32 + quad*8]);
                }

                #pragma unroll
                for (int ni = 0; ni < 8; ni++) {
                    #pragma unroll
                    for (int ks = 0; ks < 2; ks++) {
                        bf16x8 vf = *reinterpret_cast<const bf16x8*>(&sVt[ni*16 + col][ks*32 + quad*8]);
                        oacc[0][ni] = __builtin_amdgcn_mfma_f32_16x16x32_bf16(vf, pf[0][ks], oacc[0][ni], 0, 0, 0);
                        oacc[1][ni] = __builtin_amdgcn_mfma_f32_16x16x32_bf16(vf, pf[1][ks], oacc[1][ni], 0, 0, 0);
                    }
                }
            }
            __syncthreads();
        }

        #pragma unroll
        for (int g = 0; g < 2; g++) {
            const int qg = (g == 0) ? qg0 : qg1;
            float l = l_i[g];
            l += __shfl_xor(l, 16);
            l += __shfl_xor(l, 32);
            float inv = 1.0f / l;
            #pragma unroll
            for (int ni = 0; ni < 8; ni++) {
                ushort4 o4;
                o4.x = f2bf(oacc[g][ni][0] * inv);
                o4.y = f2bf(oacc[g][ni][1] * inv);
                o4.z = f2bf(oacc[g][ni][2] * inv);
                o4.w = f2bf(oacc[g][ni][3] * inv);
                *reinterpret_cast<ushort4*>(O + (rowbase + qg) * EMB + hoff + ni*16 + quad*4) = o4;
            }
        }
    }
}

extern "C" void kernel_launch(void* const* d_in, const int* in_sizes, int n_in,
                              void* d_out, int out_size, void* d_ws, size_t ws_size,
                              hipStream_t stream)
{
    const float* x  = (const float*)d_in[0];
    const float* Wq = (const float*)d_in[1];
    const float* Wk = (const float*)d_in[2];
    const float* Wv = (const float*)d_in[3];
    const float* Wo = (const float*)d_in[4];
    const float* bo = (const float*)d_in[5];
    float* out = (float*)d_out;

    unsigned short* ws = (unsigned short*)d_ws;
    const size_t XN = (size_t)MTOT * EMB;   // 16,777,216
    const size_t WN = (size_t)EMB * EMB;    //  4,194,304
    unsigned short* xb  = ws;
    unsigned short* wqb = xb  + XN;
    unsigned short* wkb = wqb + WN;
    unsigned short* wvb = wkb + WN;
    unsigned short* wob = wvb + WN;
    unsigned short* qb  = wob + WN;
    unsigned short* kb  = qb  + XN;
    unsigned short* vb  = kb  + XN;
    unsigned short* ctx = xb;  // alias: xb dead after the 3 QKV GEMMs

    {
        int total4 = (int)(XN/4 + 4*(WN/4));
        cast_all_kernel<<<total4 / 256, 256, 0, stream>>>(
            x, Wq, Wk, Wv, Wo, xb, wqb, wkb, wvb, wob);
    }

    const float scl = 0.08838834764831845f;  // 1/sqrt(128), folded into Q
    gemm256_bt<false><<<dim3(EMB/256, MTOT/256, 3), 512, 0, stream>>>(
        xb, wqb, wkb, wvb, qb, kb, vb, nullptr, MTOT, EMB, EMB, scl);

    flash_attn<<<dim3(SEQ/128/2, 16, 4), 256, 0, stream>>>(qb, kb, vb, ctx);

    gemm256_bt<true><<<dim3(EMB/256, MTOT/256, 1), 512, 0, stream>>>(
        ctx, wob, nullptr, nullptr, out, nullptr, nullptr, bo, MTOT, EMB, EMB, 1.0f);
}

// Round 3
// 595.722 us; speedup vs baseline: 2.1400x; 2.1400x over previous
//
#include <hip/hip_runtime.h>
#include <math.h>

#define EMB 2048
#define HD 128
#define SEQ 2048
#define MTOT 8192   // B*S

typedef __bf16 bf16x8 __attribute__((ext_vector_type(8)));
typedef float floatx4 __attribute__((ext_vector_type(4)));

__device__ __forceinline__ unsigned short f2bf(float f) {
    unsigned u = __float_as_uint(f);
    return (unsigned short)((u + 0x7FFFu + ((u >> 16) & 1u)) >> 16);  // RNE
}

// async global->LDS, 16B per lane. LDS dest must be wave-uniform base + lane*16.
__device__ __forceinline__ void gl_lds16(const void* g, void* lds) {
    __builtin_amdgcn_global_load_lds(
        (const __attribute__((address_space(1))) unsigned int*)g,
        (__attribute__((address_space(3))) unsigned int*)lds,
        16, 0, 0);
}

// ---------------- fused fp32 -> bf16 cast: x + 4 weights, one dispatch ------
__global__ void cast_all_kernel(const float* __restrict__ x,
                                const float* __restrict__ w0,
                                const float* __restrict__ w1,
                                const float* __restrict__ w2,
                                const float* __restrict__ w3,
                                unsigned short* __restrict__ xb,
                                unsigned short* __restrict__ wb0,
                                unsigned short* __restrict__ wb1,
                                unsigned short* __restrict__ wb2,
                                unsigned short* __restrict__ wb3)
{
    const int XN4 = MTOT * EMB / 4;       // 4,194,304
    const int WN4 = EMB * EMB / 4;        // 1,048,576
    int i = blockIdx.x * blockDim.x + threadIdx.x;
    const float* src; unsigned short* dst; int off;
    if (i < XN4) { src = x; dst = xb; off = i; }
    else {
        int j = i - XN4;
        int wsel = j >> 20;               // / WN4
        off = j & (WN4 - 1);
        switch (wsel) {
            case 0: src = w0; dst = wb0; break;
            case 1: src = w1; dst = wb1; break;
            case 2: src = w2; dst = wb2; break;
            default: src = w3; dst = wb3; break;
        }
    }
    float4 v = reinterpret_cast<const float4*>(src)[off];
    ushort4 o;
    o.x = f2bf(v.x); o.y = f2bf(v.y); o.z = f2bf(v.z); o.w = f2bf(v.w);
    reinterpret_cast<ushort4*>(dst)[off] = o;
}

// ---------------- C[M,N] = A[M,K] * Bw[N,K]^T  (bf16 MFMA) ------------------
// 256x256 tile, BK=64, 512 threads = 8 waves (2M x 4N), 8-phase schedule.
// ROUND 3: same verified schedule as round 2, addressing rewritten to fit the
// 256-reg/wave cap (512-thread block => 2 waves/SIMD => 512/2 regs).
// Round-2 spilled: ~48 LICM-hoisted LDS read addresses + 64-bit staging temps
// pushed past 256 -> scratch (VGPR=128+AGPR=128 exactly at cap, FETCH +380MB,
// MfmaUtil 11%). Key identity: XOR-swizzle term (R&7)<<4 == (col&7)<<4 is
// LANE-CONSTANT (wm*128, wn*64, mi*16 all ==0 mod 8), so every ds_read is
// base[buf][kk] + mi*2048 with compile-time immediate -> 8 base VGPRs total.

#define PH_PRE()  do { asm volatile("s_barrier" ::: "memory");               \
                       asm volatile("s_waitcnt lgkmcnt(0)" ::: "memory");    \
                       __builtin_amdgcn_sched_barrier(0);                    \
                       __builtin_amdgcn_s_setprio(1); } while (0)
#define PH_POST() do { __builtin_amdgcn_s_setprio(0);                        \
                       asm volatile("s_barrier" ::: "memory"); } while (0)

#define MFMA16(AF, BF, MI0)                                                  \
    _Pragma("unroll")                                                        \
    for (int mi = 0; mi < 4; mi++)                                           \
        _Pragma("unroll")                                                    \
        for (int ni = 0; ni < 4; ni++)                                       \
            acc[(MI0) + mi][ni] = __builtin_amdgcn_mfma_f32_16x16x32_bf16(   \
                AF[(MI0) + mi], BF[ni], acc[(MI0) + mi][ni], 0, 0, 0);

// One K-tile (4 phases). Reads 12/8/4/0; MFMA 16 per phase; stage slots S1..S4;
// VM = trailing vmcnt string ("vmcnt(4)" steady / "vmcnt(0)" tail).
#define KTILE(BUF, S1, S2, S3, S4, VM)                                       \
  do {                                                                       \
    bf16x8 a0[8], b0[4];                                                     \
    _Pragma("unroll")                                                        \
    for (int mi = 0; mi < 8; mi++)                                           \
        a0[mi] = *reinterpret_cast<const bf16x8*>(baA[BUF][0] + mi * 2048);  \
    _Pragma("unroll")                                                        \
    for (int ni = 0; ni < 4; ni++)                                           \
        b0[ni] = *reinterpret_cast<const bf16x8*>(baB[BUF][0] + ni * 2048);  \
    STAGE(S1);                                                               \
    asm volatile("s_waitcnt lgkmcnt(8)" ::: "memory");                       \
    PH_PRE();                                                                \
    MFMA16(a0, b0, 0);                                                       \
    PH_POST();                                                               \
    bf16x8 a1[8];                                                            \
    _Pragma("unroll")                                                        \
    for (int mi = 0; mi < 8; mi++)                                           \
        a1[mi] = *reinterpret_cast<const bf16x8*>(baA[BUF][1] + mi * 2048);  \
    STAGE(S2);                                                               \
    PH_PRE();                                                                \
    MFMA16(a0, b0, 4);                                                       \
    PH_POST();                                                               \
    bf16x8 b1[4];                                                            \
    _Pragma("unroll")                                                        \
    for (int ni = 0; ni < 4; ni++)                                           \
        b1[ni] = *reinterpret_cast<const bf16x8*>(baB[BUF][1] + ni * 2048);  \
    STAGE(S3);                                                               \
    PH_PRE();                                                                \
    MFMA16(a1, b1, 0);                                                       \
    PH_POST();                                                               \
    STAGE(S4);                                                               \
    asm volatile("s_waitcnt " VM ::: "memory");                              \
    PH_PRE();                                                                \
    MFMA16(a1, b1, 4);                                                       \
    PH_POST();                                                               \
  } while (0)

template<bool OUT_F32>
__global__ __launch_bounds__(512, 2)
void gemm256_bt(const unsigned short* __restrict__ A,
                const unsigned short* __restrict__ Bw0,
                const unsigned short* __restrict__ Bw1,
                const unsigned short* __restrict__ Bw2,
                void* __restrict__ Cout0,
                void* __restrict__ Cout1,
                void* __restrict__ Cout2,
                const float* __restrict__ bias,
                int M, int N, int K, float scale0)
{
    __shared__ __align__(16) unsigned short sA[2][256][64];   // 64 KB
    __shared__ __align__(16) unsigned short sB[2][256][64];   // 64 KB

    const unsigned short* Bw = (blockIdx.z == 0) ? Bw0 : (blockIdx.z == 1) ? Bw1 : Bw2;
    void* Cout = (blockIdx.z == 0) ? Cout0 : (blockIdx.z == 1) ? Cout1 : Cout2;
    const float osc = (blockIdx.z == 0) ? scale0 : 1.0f;

    const int tid  = threadIdx.x;
    const int lane = tid & 63;
    const int wave = tid >> 6;      // 0..7
    const int wm   = wave >> 2;     // 0..1  (M half)
    const int wn   = wave & 3;      // 0..3  (N quarter)
    const int col  = lane & 15;
    const int quad = lane >> 4;

    const int m0 = blockIdx.y * 256;
    const int n0 = blockIdx.x * 256;

    const int NT     = K >> 6;      // K-tiles of 64
    const int NITER  = NT >> 1;     // 2 K-tiles per iteration
    const int fourNT = NT << 2;

    // staging offsets: thread covers 16B chunks (tid) and (tid+512) of each
    // 16KB half-tile; source col pre-swizzled (inverse of read XOR).
    int off[2];
    #pragma unroll
    for (int q = 0; q < 2; q++) {
        int P = (tid + (q << 9)) << 4;                 // linear byte in half
        int r = P >> 7;                                // row 0..127
        int c = ((P & 127) ^ ((r & 7) << 4)) >> 1;     // element col
        off[q] = r * K + c;
    }

    // 8 per-lane LDS read bases (XOR term (col&7)<<4 is lane-constant).
    const int X = (col & 7) << 4;
    const char* baA[2][2];
    const char* baB[2][2];
    #pragma unroll
    for (int buf = 0; buf < 2; buf++)
        #pragma unroll
        for (int kk = 0; kk < 2; kk++) {
            int sw = (((kk << 6) | (quad << 4)) ^ X);
            baA[buf][kk] = (const char*)&sA[buf][0][0] + (wm << 14) + (col << 7) + sw;
            baB[buf][kk] = (const char*)&sB[buf][0][0] + (wn << 13) + (col << 7) + sw;
        }

    floatx4 acc[8][4];
    #pragma unroll
    for (int i = 0; i < 8; i++)
        #pragma unroll
        for (int j = 0; j < 4; j++)
            #pragma unroll
            for (int r = 0; r < 4; r++) acc[i][j][r] = 0.0f;

    auto STAGE = [&](int s) {
        if (s >= fourNT) return;                       // tail guard (uniform)
        int t = s >> 2, j = s & 3;
        int buf = t & 1;
        int k0 = t << 6;
        int jrow = (j & 1) << 7;                       // 0 or 128
        const unsigned short* src = (j < 2) ? A : Bw;
        int urow = ((j < 2) ? m0 : n0) + jrow;         // uniform
        const unsigned short* gp = src + (size_t)urow * K + k0;
        unsigned short* region = (j < 2) ? &sA[buf][jrow][0] : &sB[buf][jrow][0];
        char* ldsb = (char*)region + (wave << 10);     // wave*64*16
        #pragma unroll
        for (int q = 0; q < 2; q++)
            gl_lds16(gp + off[q], ldsb + (q << 13));   // + q*512*16
    };

    // ---- prologue: stage #0..5 = buf0 all 4 halves + buf1 A-h0, A-h1
    #pragma unroll
    for (int s = 0; s < 6; s++) STAGE(s);
    asm volatile("s_waitcnt vmcnt(4)" ::: "memory");   // K-tile 0 complete
    asm volatile("s_barrier" ::: "memory");

    #pragma unroll 1
    for (int it = 0; it < NITER - 1; ++it) {
        const int sb = 5 + (it << 3);
        KTILE(0, sb + 1, sb + 2, sb + 3, sb + 4, "vmcnt(4)");
        KTILE(1, sb + 5, sb + 6, sb + 7, sb + 8, "vmcnt(4)");
    }
    {   // last iteration: ph3/ph4 stages are guarded off -> ph4 must drain to 0
        const int sb = 5 + ((NITER - 1) << 3);
        KTILE(0, sb + 1, sb + 2, sb + 3, sb + 4, "vmcnt(0)");
        KTILE(1, sb + 5, sb + 6, sb + 7, sb + 8, "vmcnt(4)");
    }

    // ---- epilogue: same C/D mapping as the verified baseline
    #pragma unroll
    for (int mi = 0; mi < 8; mi++) {
        #pragma unroll
        for (int ni = 0; ni < 4; ni++) {
            #pragma unroll
            for (int r = 0; r < 4; r++) {
                int row = m0 + (wm << 7) + (mi << 4) + (quad << 2) + r;
                int cg  = n0 + (wn << 6) + (ni << 4) + col;
                float v = acc[mi][ni][r];
                if (OUT_F32) {
                    float bb = bias ? bias[cg] : 0.0f;
                    reinterpret_cast<float*>(Cout)[(size_t)row * N + cg] = v + bb;
                } else {
                    reinterpret_cast<unsigned short*>(Cout)[(size_t)row * N + cg] = f2bf(v * osc);
                }
            }
        }
    }
}

// ---------------- causal flash attention, S^T formulation ----------------
// (unchanged, verified)
__global__ __launch_bounds__(256, 2)
void flash_attn(const unsigned short* __restrict__ Q,
                const unsigned short* __restrict__ Kg,
                const unsigned short* __restrict__ Vg,
                unsigned short* __restrict__ O)
{
    __shared__ __align__(16) unsigned short sK[64 * 128];
    __shared__ __align__(16) unsigned short sVt[128][72];   // [d][key], padded
    __shared__ __align__(16) unsigned short sP[4][16 * 72]; // [q][key], per-wave

    const int tid  = threadIdx.x;
    const int lane = tid & 63;
    const int w    = tid >> 6;
    const int col  = lane & 15;
    const int quad = lane >> 4;

    const int h = blockIdx.y;
    const int b = blockIdx.z;
    const size_t rowbase = (size_t)b * SEQ;
    const int hoff = h * HD;

    unsigned short* sPw = sP[w];

    const int vk4 = (tid & 15) * 4;
    const int vd0 = (tid >> 4) * 8;

    #pragma unroll
    for (int phase = 0; phase < 2; phase++) {
        const int qsb = phase ? (int)blockIdx.x : (SEQ/128 - 1) - (int)blockIdx.x;
        const int qbase = qsb * 128;
        const int qg0 = qbase + w*32 + col;
        const int qg1 = qg0 + 16;

        bf16x8 qf[2][4];
        {
            const unsigned short* qr0 = Q + (rowbase + qg0) * EMB + hoff;
            const unsigned short* qr1 = Q + (rowbase + qg1) * EMB + hoff;
            #pragma unroll
            for (int ks = 0; ks < 4; ks++) {
                qf[0][ks] = *reinterpret_cast<const bf16x8*>(qr0 + ks*32 + quad*8);
                qf[1][ks] = *reinterpret_cast<const bf16x8*>(qr1 + ks*32 + quad*8);
            }
        }

        floatx4 oacc[2][8];
        #pragma unroll
        for (int g = 0; g < 2; g++)
            #pragma unroll
            for (int ni = 0; ni < 8; ni++)
                #pragma unroll
                for (int r = 0; r < 4; r++) oacc[g][ni][r] = 0.0f;
        float l_i[2] = {0.0f, 0.0f};

        const int ktmax = qbase / 64 + 1;
        for (int kt = 0; kt <= ktmax; kt++) {
            const int k0 = kt * 64;
            #pragma unroll
            for (int i = 0; i < 4; i++) {
                int c = tid + i * 256;
                int key = c >> 4;
                int dblk = (c & 15) ^ (key & 7);
                char* ldsK = (char*)sK + (size_t)(i * 256 + w * 64) * 16;
                gl_lds16(Kg + (rowbase + k0 + key) * EMB + hoff + dblk * 8, ldsK);
            }
            {
                unsigned short va[4][8];
                #pragma unroll
                for (int kk = 0; kk < 4; kk++)
                    *reinterpret_cast<int4*>(va[kk]) =
                        *reinterpret_cast<const int4*>(Vg + (rowbase + k0 + vk4 + kk) * EMB + hoff + vd0);
                #pragma unroll
                for (int j = 0; j < 8; j++) {
                    ushort4 o;
                    o.x = va[0][j]; o.y = va[1][j]; o.z = va[2][j]; o.w = va[3][j];
                    *reinterpret_cast<ushort4*>(&sVt[vd0 + j][vk4]) = o;
                }
            }
            __syncthreads();

            if (k0 <= qbase + w*32 + 31) {
                floatx4 sc[2][4];
                #pragma unroll
                for (int g = 0; g < 2; g++)
                    #pragma unroll
                    for (int ni = 0; ni < 4; ni++)
                        #pragma unroll
                        for (int r = 0; r < 4; r++) sc[g][ni][r] = 0.0f;
                #pragma unroll
                for (int ni = 0; ni < 4; ni++) {
                    #pragma unroll
                    for (int ks = 0; ks < 4; ks++) {
                        int u = (ni*16 + col) * 16 + ((ks*4 + quad) ^ (col & 7));
                        bf16x8 kf = *reinterpret_cast<const bf16x8*>(&sK[u * 8]);
                        sc[0][ni] = __builtin_amdgcn_mfma_f32_16x16x32_bf16(kf, qf[0][ks], sc[0][ni], 0, 0, 0);
                        sc[1][ni] = __builtin_amdgcn_mfma_f32_16x16x32_bf16(kf, qf[1][ks], sc[1][ni], 0, 0, 0);
                    }
                }

                const bool need_mask = (k0 + 63 > qbase + w*32);
                bf16x8 pf[2][2];

                #pragma unroll
                for (int g = 0; g < 2; g++) {
                    const int qg = (g == 0) ? qg0 : qg1;
                    if (need_mask) {
                        #pragma unroll
                        for (int ni = 0; ni < 4; ni++)
                            #pragma unroll
                            for (int r = 0; r < 4; r++) {
                                int key = k0 + ni*16 + quad*4 + r;
                                if (key > qg) sc[g][ni][r] = -1e30f;
                            }
                    }
                    float rsum = 0.0f;
                    #pragma unroll
                    for (int ni = 0; ni < 4; ni++) {
                        float p0 = __expf(sc[g][ni][0]);
                        float p1 = __expf(sc[g][ni][1]);
                        float p2 = __expf(sc[g][ni][2]);
                        float p3 = __expf(sc[g][ni][3]);
                        rsum += (p0 + p1) + (p2 + p3);
                        ushort4 pk;
                        pk.x = f2bf(p0); pk.y = f2bf(p1); pk.z = f2bf(p2); pk.w = f2bf(p3);
                        *reinterpret_cast<ushort4*>(&sPw[col*72 + ni*16 + quad*4]) = pk;
                    }
                    l_i[g] += rsum;
                    #pragma unroll
                    for (int ks = 0; ks < 2; ks++)
                        pf[g][ks] = *reinterpret_cast<const bf16x8*>(&sPw[col*72 + ks*32 + quad*8]);
                }

                #pragma unroll
                for (int ni = 0; ni < 8; ni++) {
                    #pragma unroll
                    for (int ks = 0; ks < 2; ks++) {
                        bf16x8 vf = *reinterpret_cast<const bf16x8*>(&sVt[ni*16 + col][ks*32 + quad*8]);
                        oacc[0][ni] = __builtin_amdgcn_mfma_f32_16x16x32_bf16(vf, pf[0][ks], oacc[0][ni], 0, 0, 0);
                        oacc[1][ni] = __builtin_amdgcn_mfma_f32_16x16x32_bf16(vf, pf[1][ks], oacc[1][ni], 0, 0, 0);
                    }
                }
            }
            __syncthreads();
        }

        #pragma unroll
        for (int g = 0; g < 2; g++) {
            const int qg = (g == 0) ? qg0 : qg1;
            float l = l_i[g];
            l += __shfl_xor(l, 16);
            l += __shfl_xor(l, 32);
            float inv = 1.0f / l;
            #pragma unroll
            for (int ni = 0; ni < 8; ni++) {
                ushort4 o4;
                o4.x = f2bf(oacc[g][ni][0] * inv);
                o4.y = f2bf(oacc[g][ni][1] * inv);
                o4.z = f2bf(oacc[g][ni][2] * inv);
                o4.w = f2bf(oacc[g][ni][3] * inv);
                *reinterpret_cast<ushort4*>(O + (rowbase + qg) * EMB + hoff + ni*16 + quad*4) = o4;
            }
        }
    }
}

extern "C" void kernel_launch(void* const* d_in, const int* in_sizes, int n_in,
                              void* d_out, int out_size, void* d_ws, size_t ws_size,
                              hipStream_t stream)
{
    const float* x  = (const float*)d_in[0];
    const float* Wq = (const float*)d_in[1];
    const float* Wk = (const float*)d_in[2];
    const float* Wv = (const float*)d_in[3];
    const float* Wo = (const float*)d_in[4];
    const float* bo = (const float*)d_in[5];
    float* out = (float*)d_out;

    unsigned short* ws = (unsigned short*)d_ws;
    const size_t XN = (size_t)MTOT * EMB;   // 16,777,216
    const size_t WN = (size_t)EMB * EMB;    //  4,194,304
    unsigned short* xb  = ws;
    unsigned short* wqb = xb  + XN;
    unsigned short* wkb = wqb + WN;
    unsigned short* wvb = wkb + WN;
    unsigned short* wob = wvb + WN;
    unsigned short* qb  = wob + WN;
    unsigned short* kb  = qb  + XN;
    unsigned short* vb  = kb  + XN;
    unsigned short* ctx = xb;  // alias: xb dead after the 3 QKV GEMMs

    {
        int total4 = (int)(XN/4 + 4*(WN/4));
        cast_all_kernel<<<total4 / 256, 256, 0, stream>>>(
            x, Wq, Wk, Wv, Wo, xb, wqb, wkb, wvb, wob);
    }

    const float scl = 0.08838834764831845f;  // 1/sqrt(128), folded into Q
    gemm256_bt<false><<<dim3(EMB/256, MTOT/256, 3), 512, 0, stream>>>(
        xb, wqb, wkb, wvb, qb, kb, vb, nullptr, MTOT, EMB, EMB, scl);

    flash_attn<<<dim3(SEQ/128/2, 16, 4), 256, 0, stream>>>(qb, kb, vb, ctx);

    gemm256_bt<true><<<dim3(EMB/256, MTOT/256, 1), 512, 0, stream>>>(
        ctx, wob, nullptr, nullptr, out, nullptr, nullptr, bo, MTOT, EMB, EMB, 1.0f);
}